// Round 21
// baseline (441.048 us; speedup 1.0000x reference)
//
#include <hip/hip_runtime.h>
#include <hip/hip_fp16.h>

// Problem constants
constexpr int QN  = 10001;   // questions (Q+1)
constexpr int BB  = 512;     // batch
constexpr int TT  = 200;     // seq len
constexpr int QPB = 32;      // questions per block in k_perq

__device__ __forceinline__ float sigm(float x) { return 1.f / (1.f + __expf(-x)); }
__device__ __forceinline__ float tanh_fast(float x) { return 1.f - 2.f / (1.f + __expf(2.f * x)); }

__device__ __forceinline__ unsigned packh_rtne(float lo, float hi) {
    return ((unsigned)__half_as_ushort(__float2half(hi)) << 16) |
            (unsigned)__half_as_ushort(__float2half(lo));
}

typedef _Float16 half2_t __attribute__((ext_vector_type(2)));
typedef float f4v __attribute__((ext_vector_type(4)));
__device__ __forceinline__ half2_t u2h(unsigned u) {
    union { unsigned u; half2_t h; } x; x.u = u; return x.h;
}

#if __has_builtin(__builtin_amdgcn_fdot2)
__device__ __forceinline__ float fdot2u(unsigned wu, unsigned hu, float acc) {
    return __builtin_amdgcn_fdot2(u2h(wu), u2h(hu), acc, false);
}
#else
__device__ __forceinline__ float fdot2u(unsigned wu, unsigned hu, float acc) {
    float wlo = __half2float(__ushort_as_half((unsigned short)(wu & 0xffffu)));
    float whi = __half2float(__ushort_as_half((unsigned short)(wu >> 16)));
    float hlo = __half2float(__ushort_as_half((unsigned short)(hu & 0xffffu)));
    float hhi = __half2float(__ushort_as_half((unsigned short)(hu >> 16)));
    return acc + wlo * hlo + whi * hhi;
}
#endif

// async global->LDS, 16B per lane
typedef const __attribute__((address_space(1))) void cgv_t;
typedef __attribute__((address_space(3))) void lv_t;
__device__ __forceinline__ void glds16(const float* g, float* l) {
    __builtin_amdgcn_global_load_lds((cgv_t*)g, (lv_t*)l, 16, 0, 0);
}

// ---------------------------------------------------------------------------
// Kernel 1: precomputed tables (r18 form).
// ---------------------------------------------------------------------------
__global__ void k_tables(const float* __restrict__ E_c, const float* __restrict__ E_it,
                         const float* __restrict__ E_ut, const float* __restrict__ E_nh,
                         const float* __restrict__ W_fuse, const float* __restrict__ b_fuse,
                         const float* __restrict__ W_ih, const float* __restrict__ b_ih,
                         const float* __restrict__ la_W1, const float* __restrict__ la_W2,
                         float* __restrict__ T_c, float* __restrict__ T_it,
                         float* __restrict__ T_ut, float* __restrict__ T_nh, float* __restrict__ T_na,
                         float* __restrict__ bias0, float* __restrict__ Vcorr,
                         unsigned* __restrict__ w1h, unsigned* __restrict__ w2h)
{
    int blk = blockIdx.x, j = threadIdx.x; // 192 threads
    __shared__ float s_e[64];
    __shared__ float s_t[64];
    const int ilv4 = (j & 63) * 4 + (j >> 6);

    if (blk < 201) {
        if (j < 64) s_e[j] = E_c[blk * 64 + j];
        __syncthreads();
        float a = 0.f;
        #pragma unroll
        for (int k = 0; k < 64; k++) a += W_ih[j * 320 + 64 + k] * s_e[k];
        T_c[blk * 192 + j] = a;
    } else if (blk < 302) {
        int r = blk - 201;
        if (j < 64) s_e[j] = E_it[r * 64 + j];
        __syncthreads();
        float a = 0.f;
        #pragma unroll
        for (int k = 0; k < 64; k++) a += W_ih[j * 320 + 192 + k] * s_e[k];
        T_it[r * 256 + ilv4] = a;
    } else if (blk < 605) {
        int which = (blk - 302) / 101;
        int r     = (blk - 302) % 101;
        const float* E = (which == 0) ? E_ut : E_nh;
        int fofs = which * 64;
        if (j < 64) s_e[j] = E[r * 64 + j];
        __syncthreads();
        if (j < 64) {
            float a = 0.f;
            #pragma unroll
            for (int d = 0; d < 64; d++) a += W_fuse[j * 192 + fofs + d] * s_e[d];
            s_t[j] = a;
        }
        __syncthreads();
        float a = 0.f;
        #pragma unroll
        for (int e = 0; e < 64; e++) a += W_ih[j * 320 + 256 + e] * s_t[e];
        float* outp = (which == 0) ? T_ut : ((which == 1) ? T_nh : T_na);
        outp[r * 256 + ilv4] = a;
    } else if (blk == 605) {
        float a = b_ih[j];
        #pragma unroll
        for (int e = 0; e < 64; e++) a += W_ih[j * 320 + 256 + e] * b_fuse[e];
        bias0[j] = a;
        float v = 0.f;
        #pragma unroll
        for (int k = 0; k < 64; k++) v += W_ih[j * 320 + 128 + k];
        Vcorr[j] = v;
    } else if (blk < 628) {
        int i = (blk - 606) * 192 + j;      // 132*32 = 4224 exact
        int m = i >> 5, k = i & 31;
        w1h[i] = packh_rtne(la_W1[m * 64 + 2 * k], la_W1[m * 64 + 2 * k + 1]);
    } else {
        int i = (blk - 628) * 192 + j;
        if (i < 200 * 68) {
            int c = i / 68, k = i - c * 68;
            w2h[i] = (k < 66) ? packh_rtne(la_W2[c * 132 + 2 * k], la_W2[c * 132 + 2 * k + 1]) : 0u;
        }
    }
}

// ---------------------------------------------------------------------------
// Kernel 2: per-question precompute (r19 form, 4-accumulator rowdot).
// ---------------------------------------------------------------------------
__global__ void __launch_bounds__(192) k_perq(
    const float* __restrict__ E_q, const float* __restrict__ W_ih,
    const float* __restrict__ qd_W1, const float* __restrict__ qd_b1,
    const float* __restrict__ qd_W2, const float* __restrict__ qd_b2,
    const float* __restrict__ dc_W1, const float* __restrict__ dc_b1,
    const float* __restrict__ dc_W2, const float* __restrict__ dc_b2,
    const int* __restrict__ q2c, const int* __restrict__ q2cm,
    const float* __restrict__ T_c,
    float* __restrict__ Xq, float* __restrict__ disc,
    float* __restrict__ qds, float* __restrict__ wdk)
{
    __shared__ float s_wbuf[192 * 66];
    __shared__ float s_qe[QPB][64];
    __shared__ float s_wq[QPB][4];
    __shared__ int   s_cq[QPB][4];
    __shared__ float s_hidw[3][136];

    const int tid = threadIdx.x, w = tid >> 6, l = tid & 63;
    const int q0 = blockIdx.x * QPB;

    for (int i = tid; i < 132 * 64; i += 192)
        s_wbuf[(i >> 6) * 66 + (i & 63)] = qd_W1[i];
    for (int i = tid; i < 32 * 64; i += 192)
        s_wbuf[(132 + (i >> 6)) * 66 + (i & 63)] = dc_W1[i];
    for (int i = tid; i < QPB * 64; i += 192) {
        int qq = i >> 6, q = q0 + qq;
        s_qe[qq][i & 63] = E_q[(q < QN ? q : 0) * 64 + (i & 63)];
    }
    __syncthreads();

    for (int qq = w; qq < QPB; qq += 3) {
        int q = q0 + qq;
        bool valid = q < QN;
        int qc = valid ? q : 0;
        int cc[4], mm[4];
        #pragma unroll
        for (int k = 0; k < 4; k++) { cc[k] = q2c[qc * 4 + k]; mm[k] = q2cm[qc * 4 + k]; }

        float qe[64];
        #pragma unroll
        for (int k4 = 0; k4 < 16; k4++) {
            float4 v = *(const float4*)(&s_qe[qq][k4 * 4]);
            qe[4 * k4] = v.x; qe[4 * k4 + 1] = v.y; qe[4 * k4 + 2] = v.z; qe[4 * k4 + 3] = v.w;
        }

        auto rowdot = [&](int r) {
            const float* wr = s_wbuf + r * 66;
            float a0 = 0.f, a1 = 0.f, a2 = 0.f, a3 = 0.f;
            #pragma unroll
            for (int jj = 0; jj < 32; jj += 4) {
                float2 w0 = *(const float2*)(wr + 2 * jj);
                float2 w1 = *(const float2*)(wr + 2 * jj + 2);
                float2 w2 = *(const float2*)(wr + 2 * jj + 4);
                float2 w3 = *(const float2*)(wr + 2 * jj + 6);
                a0 += w0.x * qe[2 * jj]     + w0.y * qe[2 * jj + 1];
                a1 += w1.x * qe[2 * jj + 2] + w1.y * qe[2 * jj + 3];
                a2 += w2.x * qe[2 * jj + 4] + w2.y * qe[2 * jj + 5];
                a3 += w3.x * qe[2 * jj + 6] + w3.y * qe[2 * jj + 7];
            }
            return (a0 + a1) + (a2 + a3);
        };

        s_hidw[w][l]      = fmaxf(rowdot(l)      + qd_b1[l],      0.f);
        s_hidw[w][64 + l] = fmaxf(rowdot(64 + l) + qd_b1[64 + l], 0.f);
        if (l < 4)
            s_hidw[w][128 + l] = fmaxf(rowdot(128 + l) + qd_b1[128 + l], 0.f);
        float dch = 0.f;
        if (l < 32) dch = fmaxf(rowdot(132 + l) + dc_b1[l], 0.f);

        int g = l >> 4, li = l & 15;
        int c = cc[g];
        float acc = 0.f;
        #pragma unroll
        for (int i = 0; i < 9; i++) {
            int m = li + 16 * i;
            if (m < 132) acc += qd_W2[c * 132 + m] * s_hidw[w][m];
        }
        acc += __shfl_xor(acc, 1); acc += __shfl_xor(acc, 2);
        acc += __shfl_xor(acc, 4); acc += __shfl_xor(acc, 8);
        float r0 = __shfl(acc, 0), r1 = __shfl(acc, 16);
        float r2 = __shfl(acc, 32), r3 = __shfl(acc, 48);

        float raw[4] = { sigm(r0 + qd_b2[cc[0]]), sigm(r1 + qd_b2[cc[1]]),
                         sigm(r2 + qd_b2[cc[2]]), sigm(r3 + qd_b2[cc[3]]) };
        float rel[4];
        #pragma unroll
        for (int k = 0; k < 4; k++) rel[k] = raw[k] * (float)mm[k];
        float sr = rel[0] + rel[1] + rel[2] + rel[3] + 1e-6f;

        float qsum = 0.f, wdv[4];
        #pragma unroll
        for (int k = 0; k < 4; k++) {
            float wd = 0.f;
            if (mm[k]) {
                bool dup = false;
                for (int jj = 0; jj < k; jj++)
                    if (mm[jj] && cc[jj] == cc[k]) dup = true;
                if (!dup) { wd = 1.f; qsum += raw[k]; }
            }
            wdv[k] = wd;
        }
        if (l < 4) { s_wq[qq][l] = rel[l] / sr; s_cq[qq][l] = cc[l]; }
        if (valid) {
            if (l < 4) wdk[q * 4 + l] = wdv[l];
            if (l == 0) qds[q] = qsum;
        }

        float dv = (l < 32) ? dch * dc_W2[l] : 0.f;
        dv += __shfl_xor(dv, 1);  dv += __shfl_xor(dv, 2);
        dv += __shfl_xor(dv, 4);  dv += __shfl_xor(dv, 8);
        dv += __shfl_xor(dv, 16);
        if (valid && l == 0) disc[q] = sigm(dv + dc_b2[0]) * 10.f;
    }

    __syncthreads();
    for (int i = tid; i < 192 * 64; i += 192) {
        int r = i >> 6, k = i & 63;
        s_wbuf[r * 66 + k] = W_ih[r * 320 + k];
    }
    __syncthreads();

    for (int qq = w; qq < QPB; qq += 3) {
        int q = q0 + qq;
        if (q >= QN) continue;

        float qe[64];
        #pragma unroll
        for (int k4 = 0; k4 < 16; k4++) {
            float4 v = *(const float4*)(&s_qe[qq][k4 * 4]);
            qe[4 * k4] = v.x; qe[4 * k4 + 1] = v.y; qe[4 * k4 + 2] = v.z; qe[4 * k4 + 3] = v.w;
        }
        float wq[4]; int cq[4];
        #pragma unroll
        for (int k = 0; k < 4; k++) { wq[k] = s_wq[qq][k]; cq[k] = s_cq[qq][k]; }

        #pragma unroll
        for (int rr = 0; rr < 3; rr++) {
            int row = rr * 64 + l;
            const float* wr = s_wbuf + row * 66;
            float a0 = 0.f, a1 = 0.f, a2 = 0.f, a3 = 0.f;
            #pragma unroll
            for (int jj = 0; jj < 32; jj += 4) {
                float2 w0 = *(const float2*)(wr + 2 * jj);
                float2 w1 = *(const float2*)(wr + 2 * jj + 2);
                float2 w2 = *(const float2*)(wr + 2 * jj + 4);
                float2 w3 = *(const float2*)(wr + 2 * jj + 6);
                a0 += w0.x * qe[2 * jj]     + w0.y * qe[2 * jj + 1];
                a1 += w1.x * qe[2 * jj + 2] + w1.y * qe[2 * jj + 3];
                a2 += w2.x * qe[2 * jj + 4] + w2.y * qe[2 * jj + 5];
                a3 += w3.x * qe[2 * jj + 6] + w3.y * qe[2 * jj + 7];
            }
            float a = (a0 + a1) + (a2 + a3);
            #pragma unroll
            for (int k = 0; k < 4; k++) a += wq[k] * T_c[cq[k] * 192 + row];
            Xq[q * 256 + l * 4 + rr] = a;
        }
    }
}

// ---------------------------------------------------------------------------
// Kernel 3 v21: FUSED, ONE WAVE per block. r19/r20 proof: weight residency
// requires waves_per_eu(max=1), but a 4-wave block at max=1 serializes the
// grid into 2 passes. A 64-thread block at (1,1) gets 2 blocks/CU (LDS
// 77.8KB x 2 < 160KB; 2 waves spread over 4 SIMDs) -> single pass with the
// r15 scan config (139us, VGPR 132). The SAME wave then loops the r18
// readout over its sample's 199 tokens (4 passes of 64 threads). No
// __syncthreads anywhere: single-wave LDS ordering (r10-r17 pattern).
// ---------------------------------------------------------------------------
__global__ void
__launch_bounds__(64)
__attribute__((amdgpu_waves_per_eu(1, 1)))
k_gru(
    const float* __restrict__ W_hh, const float* __restrict__ b_hh,
    const float* __restrict__ XqI, const float* __restrict__ TitI, const float* __restrict__ TutI,
    const float* __restrict__ TnhI, const float* __restrict__ TnaI,
    const float* __restrict__ b0, const float* __restrict__ vc,
    const int* __restrict__ qseq, const int* __restrict__ cseq, const int* __restrict__ itseq,
    const int* __restrict__ utseq, const int* __restrict__ nhseq, const int* __restrict__ naseq,
    const unsigned* __restrict__ w1h, const float* __restrict__ la_b1,
    const unsigned* __restrict__ w2h, const float* __restrict__ la_b2,
    const int* __restrict__ q2c,
    const float* __restrict__ disc, const float* __restrict__ qds,
    const float* __restrict__ wdk, float* __restrict__ out)
{
    const int j = threadIdx.x, b = blockIdx.x;
    const int j4 = 4 * j;

    __shared__ float s_gb[4][5][64][4];   // 20KB gather slots
    __shared__ int s_ix[6 * TT];          // 4.8KB indices
    __shared__ unsigned s_hp[32];         // packed h
    __shared__ float s_lat[TT][66];       // 52.8KB h history (pad-66)

    const int base = b * TT;
    for (int i = j; i < TT; i += 64) {
        s_ix[i]          = qseq[base + i];
        s_ix[TT + i]     = cseq[base + i];
        s_ix[2 * TT + i] = itseq[base + i];
        s_ix[3 * TT + i] = utseq[base + i];
        s_ix[4 * TT + i] = nhseq[base + i];
        s_ix[5 * TT + i] = naseq[base + i];
    }

    // lane j's three gate rows of W_hh, packed f16: 96 VGPRs
    unsigned wr[32], wz[32], wn[32];
    {
        const float4* p0 = (const float4*)(W_hh + j * 64);
        const float4* p1 = (const float4*)(W_hh + (64 + j) * 64);
        const float4* p2 = (const float4*)(W_hh + (128 + j) * 64);
        #pragma unroll
        for (int k = 0; k < 16; k++) {
            float4 a = p0[k], bq = p1[k], c = p2[k];
            wr[2 * k] = packh_rtne(a.x, a.y);  wr[2 * k + 1] = packh_rtne(a.z, a.w);
            wz[2 * k] = packh_rtne(bq.x, bq.y); wz[2 * k + 1] = packh_rtne(bq.z, bq.w);
            wn[2 * k] = packh_rtne(c.x, c.y);  wn[2 * k + 1] = packh_rtne(c.z, c.w);
        }
    }
    #pragma unroll
    for (int k = 0; k < 32; k++)
        asm volatile("" : "+v"(wr[k]), "+v"(wz[k]), "+v"(wn[k]));

    const float bhr = b_hh[j], bhz = b_hh[64 + j], bhn = b_hh[128 + j];
    const float b0r = b0[j],   b0z = b0[64 + j],   b0n = b0[128 + j];
    const float vcr = vc[j],   vcz = vc[64 + j],   vcn = vc[128 + j];

    if (j < 32) s_hp[j] = 0u;
    asm volatile("s_waitcnt lgkmcnt(0)" ::: "memory");   // staging + h-init visible

    float hj = 0.f;
    float cA, cB, cC, cD;

#define GISSUE(S, CCV, tt) { \
        int q_ = s_ix[tt], c_ = s_ix[TT + tt], it_ = s_ix[2 * TT + tt]; \
        int ut_ = s_ix[3 * TT + tt], nh_ = s_ix[4 * TT + tt], na_ = s_ix[5 * TT + tt]; \
        CCV = (float)c_; \
        glds16(XqI  + q_  * 256 + j4, &s_gb[S][0][0][0]); \
        glds16(TitI + it_ * 256 + j4, &s_gb[S][1][0][0]); \
        glds16(TutI + ut_ * 256 + j4, &s_gb[S][2][0][0]); \
        glds16(TnhI + nh_ * 256 + j4, &s_gb[S][3][0][0]); \
        glds16(TnaI + na_ * 256 + j4, &s_gb[S][4][0][0]); \
    }

#define STEP(S, CCV, tcur, WN, REF) { \
        asm volatile("s_waitcnt vmcnt(" WN ")" ::: "memory"); \
        f4v g0 = *(const f4v*)&s_gb[S][0][j][0]; \
        f4v g1 = *(const f4v*)&s_gb[S][1][j][0]; \
        f4v g2 = *(const f4v*)&s_gb[S][2][j][0]; \
        f4v g3 = *(const f4v*)&s_gb[S][3][j][0]; \
        f4v g4 = *(const f4v*)&s_gb[S][4][j][0]; \
        asm volatile("s_waitcnt lgkmcnt(0)" ::: "memory"); \
        float xr = b0r + CCV * vcr + (((g0.x + g1.x) + (g2.x + g3.x)) + g4.x); \
        float xz = b0z + CCV * vcz + (((g0.y + g1.y) + (g2.y + g3.y)) + g4.y); \
        float xn = b0n + CCV * vcn + (((g0.z + g1.z) + (g2.z + g3.z)) + g4.z); \
        if (REF) GISSUE(S, CCV, (tcur) + 4); \
        float ar0 = 0.f, ar1 = 0.f, ar2 = 0.f, ar3 = 0.f; \
        float az0 = 0.f, az1 = 0.f, az2 = 0.f, az3 = 0.f; \
        float an0 = 0.f, an1 = 0.f, an2 = 0.f, an3 = 0.f; \
        const uint4* hp4 = (const uint4*)s_hp; \
        _Pragma("unroll") \
        for (int k4 = 0; k4 < 8; k4++) { \
            uint4 hh = hp4[k4]; \
            ar0 = fdot2u(wr[4 * k4 + 0], hh.x, ar0); \
            ar1 = fdot2u(wr[4 * k4 + 1], hh.y, ar1); \
            ar2 = fdot2u(wr[4 * k4 + 2], hh.z, ar2); \
            ar3 = fdot2u(wr[4 * k4 + 3], hh.w, ar3); \
            az0 = fdot2u(wz[4 * k4 + 0], hh.x, az0); \
            az1 = fdot2u(wz[4 * k4 + 1], hh.y, az1); \
            az2 = fdot2u(wz[4 * k4 + 2], hh.z, az2); \
            az3 = fdot2u(wz[4 * k4 + 3], hh.w, az3); \
            an0 = fdot2u(wn[4 * k4 + 0], hh.x, an0); \
            an1 = fdot2u(wn[4 * k4 + 1], hh.y, an1); \
            an2 = fdot2u(wn[4 * k4 + 2], hh.z, an2); \
            an3 = fdot2u(wn[4 * k4 + 3], hh.w, an3); \
        } \
        float ar = ((ar0 + ar1) + (ar2 + ar3)) + bhr; \
        float az = ((az0 + az1) + (az2 + az3)) + bhz; \
        float an = ((an0 + an1) + (an2 + an3)) + bhn; \
        float r = sigm(xr + ar); \
        float z = sigm(xz + az); \
        float n = tanh_fast(xn + r * an); \
        hj = (1.f - z) * n + z * hj; \
        s_lat[tcur][j] = hj; \
        float hnb = __shfl_xor(hj, 1); \
        unsigned pk = (j & 1) ? packh_rtne(hnb, hj) : packh_rtne(hj, hnb); \
        if (!(j & 1)) s_hp[j >> 1] = pk; \
    }

    GISSUE(0, cA, 0);
    GISSUE(1, cB, 1);
    GISSUE(2, cC, 2);
    GISSUE(3, cD, 3);

    STEP(0, cA, 0, "15", 1);
    STEP(1, cB, 1, "15", 1);
    STEP(2, cC, 2, "15", 1);
    STEP(3, cD, 3, "15", 1);

    for (int t = 4; t <= TT - 8; t += 4) {
        STEP(0, cA, t,     "15", 1);
        STEP(1, cB, t + 1, "15", 1);
        STEP(2, cC, t + 2, "15", 1);
        STEP(3, cD, t + 3, "15", 1);
    }
    STEP(0, cA, TT - 4, "15", 0);
    STEP(1, cB, TT - 3, "10", 0);
    STEP(2, cC, TT - 2, "5",  0);
    STEP(3, cD, TT - 1, "0",  0);
#undef STEP
#undef GISSUE

    asm volatile("s_waitcnt lgkmcnt(0)" ::: "memory");   // s_lat complete

    // ---- readout: same wave loops over this sample's 199 tokens ----
    for (int t = j; t < TT - 1; t += 64) {
        unsigned L[32];
        {
            const float4* lp = (const float4*)&s_lat[t][0];
            #pragma unroll
            for (int kk = 0; kk < 16; kk++) {
                float4 v = lp[kk];
                L[2 * kk]     = packh_rtne(v.x, v.y);
                L[2 * kk + 1] = packh_rtne(v.z, v.w);
            }
        }

        unsigned hidpk[66];
        float hprev = 0.f;
        #pragma unroll
        for (int m = 0; m < 132; m++) {
            const unsigned* w1r = w1h + m * 32;
            float a0 = 0.f, a1 = 0.f, a2 = 0.f, a3 = 0.f;
            #pragma unroll
            for (int k = 0; k < 32; k += 4) {
                a0 = fdot2u(w1r[k],     L[k],     a0);
                a1 = fdot2u(w1r[k + 1], L[k + 1], a1);
                a2 = fdot2u(w1r[k + 2], L[k + 2], a2);
                a3 = fdot2u(w1r[k + 3], L[k + 3], a3);
            }
            float hm = fmaxf(((a0 + a1) + (a2 + a3)) + la_b1[m], 0.f);
            if (m & 1) hidpk[m >> 1] = packh_rtne(hprev, hm);
            else hprev = hm;
        }

        int q = s_ix[t + 1];
        float u[4];
        #pragma unroll
        for (int kc = 0; kc < 4; kc++) {
            int c = q2c[q * 4 + kc];
            const unsigned* w2r = w2h + c * 68;
            float u0 = 0.f, u1 = 0.f;
            #pragma unroll
            for (int k = 0; k < 66; k += 2) {
                u0 = fdot2u(w2r[k],     hidpk[k],     u0);
                u1 = fdot2u(w2r[k + 1], hidpk[k + 1], u1);
            }
            u[kc] = u0 + u1 + la_b2[c];
        }

        float us = 0.f;
        #pragma unroll
        for (int kc = 0; kc < 4; kc++) us += wdk[q * 4 + kc] * sigm(u[kc]);
        float qs = qds[q];
        float y = disc[q] * (us - qs) / (qs + 1e-6f);
        out[(size_t)b * (TT - 1) + t] = sigm(y);
    }
}

// ---------------------------------------------------------------------------
extern "C" void kernel_launch(void* const* d_in, const int* in_sizes, int n_in,
                              void* d_out, int out_size, void* d_ws, size_t ws_size,
                              hipStream_t stream)
{
    const float* E_q    = (const float*)d_in[0];
    const float* E_c    = (const float*)d_in[1];
    const float* E_it   = (const float*)d_in[2];
    const float* E_ut   = (const float*)d_in[3];
    const float* E_nh   = (const float*)d_in[4];
    const float* W_fuse = (const float*)d_in[5];
    const float* b_fuse = (const float*)d_in[6];
    const float* W_ih   = (const float*)d_in[7];
    const float* b_ih   = (const float*)d_in[8];
    const float* W_hh   = (const float*)d_in[9];
    const float* b_hh   = (const float*)d_in[10];
    const float* qd_W1  = (const float*)d_in[11];
    const float* qd_b1  = (const float*)d_in[12];
    const float* qd_W2  = (const float*)d_in[13];
    const float* qd_b2  = (const float*)d_in[14];
    const float* la_W1  = (const float*)d_in[15];
    const float* la_b1  = (const float*)d_in[16];
    const float* la_W2  = (const float*)d_in[17];
    const float* la_b2  = (const float*)d_in[18];
    const float* dc_W1  = (const float*)d_in[19];
    const float* dc_b1  = (const float*)d_in[20];
    const float* dc_W2  = (const float*)d_in[21];
    const float* dc_b2  = (const float*)d_in[22];

    int off = (in_sizes[23] == QN * 200) ? 1 : 0;
    const int* qseq  = (const int*)d_in[23 + off];
    const int* cseq  = (const int*)d_in[24 + off];
    const int* itseq = (const int*)d_in[25 + off];
    const int* utseq = (const int*)d_in[26 + off];
    const int* nhseq = (const int*)d_in[27 + off];
    const int* naseq = (const int*)d_in[28 + off];
    const int* q2c   = (const int*)d_in[29 + off];
    const int* q2cm  = (const int*)d_in[30 + off];

    float* ws = (float*)d_ws;
    size_t o = 0;
    float* T_c  = ws + o; o += (size_t)201 * 192;
    float* Tit  = ws + o; o += (size_t)101 * 256;
    float* Tut  = ws + o; o += (size_t)101 * 256;
    float* Tnh  = ws + o; o += (size_t)101 * 256;
    float* Tna  = ws + o; o += (size_t)101 * 256;
    float* b0   = ws + o; o += 192;
    float* vc   = ws + o; o += 192;
    float* Xq   = ws + o; o += (size_t)QN * 256;
    float* disc = ws + o; o += QN;
    float* qds  = ws + o; o += QN;
    float* wdk  = ws + o; o += (size_t)QN * 4;
    unsigned* w1h = (unsigned*)(ws + o); o += (size_t)132 * 32;
    unsigned* w2h = (unsigned*)(ws + o); o += (size_t)200 * 68;

    float* outp = (float*)d_out;

    k_tables<<<699, 192, 0, stream>>>(E_c, E_it, E_ut, E_nh, W_fuse, b_fuse, W_ih, b_ih,
                                      la_W1, la_W2,
                                      T_c, Tit, Tut, Tnh, Tna, b0, vc, w1h, w2h);
    k_perq<<<(QN + QPB - 1) / QPB, 192, 0, stream>>>(E_q, W_ih, qd_W1, qd_b1, qd_W2, qd_b2,
                                                     dc_W1, dc_b1, dc_W2, dc_b2, q2c, q2cm, T_c,
                                                     Xq, disc, qds, wdk);
    k_gru<<<BB, 64, 0, stream>>>(W_hh, b_hh, Xq, Tit, Tut, Tnh, Tna, b0, vc,
                                 qseq, cseq, itseq, utseq, nhseq, naseq,
                                 w1h, la_b1, w2h, la_b2, q2c, disc, qds, wdk, outp);
}

// Round 22
// 394.041 us; speedup vs baseline: 1.1193x; 1.1193x over previous
//
#include <hip/hip_runtime.h>
#include <hip/hip_fp16.h>

// Problem constants
constexpr int QN  = 10001;   // questions (Q+1)
constexpr int BB  = 512;     // batch
constexpr int TT  = 200;     // seq len
constexpr int QPB = 32;      // questions per block in k_perq

__device__ __forceinline__ float sigm(float x) { return 1.f / (1.f + __expf(-x)); }
__device__ __forceinline__ float tanh_fast(float x) { return 1.f - 2.f / (1.f + __expf(2.f * x)); }

__device__ __forceinline__ unsigned packh_rtne(float lo, float hi) {
    return ((unsigned)__half_as_ushort(__float2half(hi)) << 16) |
            (unsigned)__half_as_ushort(__float2half(lo));
}

typedef _Float16 half2_t __attribute__((ext_vector_type(2)));
typedef float f4v __attribute__((ext_vector_type(4)));
__device__ __forceinline__ half2_t u2h(unsigned u) {
    union { unsigned u; half2_t h; } x; x.u = u; return x.h;
}

#if __has_builtin(__builtin_amdgcn_fdot2)
__device__ __forceinline__ float fdot2u(unsigned wu, unsigned hu, float acc) {
    return __builtin_amdgcn_fdot2(u2h(wu), u2h(hu), acc, false);
}
#else
__device__ __forceinline__ float fdot2u(unsigned wu, unsigned hu, float acc) {
    float wlo = __half2float(__ushort_as_half((unsigned short)(wu & 0xffffu)));
    float whi = __half2float(__ushort_as_half((unsigned short)(wu >> 16)));
    float hlo = __half2float(__ushort_as_half((unsigned short)(hu & 0xffffu)));
    float hhi = __half2float(__ushort_as_half((unsigned short)(hu >> 16)));
    return acc + wlo * hlo + whi * hhi;
}
#endif

// async global->LDS, 16B per lane
typedef const __attribute__((address_space(1))) void cgv_t;
typedef __attribute__((address_space(3))) void lv_t;
__device__ __forceinline__ void glds16(const float* g, float* l) {
    __builtin_amdgcn_global_load_lds((cgv_t*)g, (lv_t*)l, 16, 0, 0);
}

// ---------------------------------------------------------------------------
// Kernel 1: precomputed tables (r18 form).
// ---------------------------------------------------------------------------
__global__ void k_tables(const float* __restrict__ E_c, const float* __restrict__ E_it,
                         const float* __restrict__ E_ut, const float* __restrict__ E_nh,
                         const float* __restrict__ W_fuse, const float* __restrict__ b_fuse,
                         const float* __restrict__ W_ih, const float* __restrict__ b_ih,
                         const float* __restrict__ la_W1, const float* __restrict__ la_W2,
                         float* __restrict__ T_c, float* __restrict__ T_it,
                         float* __restrict__ T_ut, float* __restrict__ T_nh, float* __restrict__ T_na,
                         float* __restrict__ bias0, float* __restrict__ Vcorr,
                         unsigned* __restrict__ w1h, unsigned* __restrict__ w2h)
{
    int blk = blockIdx.x, j = threadIdx.x; // 192 threads
    __shared__ float s_e[64];
    __shared__ float s_t[64];
    const int ilv4 = (j & 63) * 4 + (j >> 6);

    if (blk < 201) {
        if (j < 64) s_e[j] = E_c[blk * 64 + j];
        __syncthreads();
        float a = 0.f;
        #pragma unroll
        for (int k = 0; k < 64; k++) a += W_ih[j * 320 + 64 + k] * s_e[k];
        T_c[blk * 192 + j] = a;
    } else if (blk < 302) {
        int r = blk - 201;
        if (j < 64) s_e[j] = E_it[r * 64 + j];
        __syncthreads();
        float a = 0.f;
        #pragma unroll
        for (int k = 0; k < 64; k++) a += W_ih[j * 320 + 192 + k] * s_e[k];
        T_it[r * 256 + ilv4] = a;
    } else if (blk < 605) {
        int which = (blk - 302) / 101;
        int r     = (blk - 302) % 101;
        const float* E = (which == 0) ? E_ut : E_nh;
        int fofs = which * 64;
        if (j < 64) s_e[j] = E[r * 64 + j];
        __syncthreads();
        if (j < 64) {
            float a = 0.f;
            #pragma unroll
            for (int d = 0; d < 64; d++) a += W_fuse[j * 192 + fofs + d] * s_e[d];
            s_t[j] = a;
        }
        __syncthreads();
        float a = 0.f;
        #pragma unroll
        for (int e = 0; e < 64; e++) a += W_ih[j * 320 + 256 + e] * s_t[e];
        float* outp = (which == 0) ? T_ut : ((which == 1) ? T_nh : T_na);
        outp[r * 256 + ilv4] = a;
    } else if (blk == 605) {
        float a = b_ih[j];
        #pragma unroll
        for (int e = 0; e < 64; e++) a += W_ih[j * 320 + 256 + e] * b_fuse[e];
        bias0[j] = a;
        float v = 0.f;
        #pragma unroll
        for (int k = 0; k < 64; k++) v += W_ih[j * 320 + 128 + k];
        Vcorr[j] = v;
    } else if (blk < 628) {
        int i = (blk - 606) * 192 + j;      // 132*32 = 4224 exact
        int m = i >> 5, k = i & 31;
        w1h[i] = packh_rtne(la_W1[m * 64 + 2 * k], la_W1[m * 64 + 2 * k + 1]);
    } else {
        int i = (blk - 628) * 192 + j;
        if (i < 200 * 68) {
            int c = i / 68, k = i - c * 68;
            w2h[i] = (k < 66) ? packh_rtne(la_W2[c * 132 + 2 * k], la_W2[c * 132 + 2 * k + 1]) : 0u;
        }
    }
}

// ---------------------------------------------------------------------------
// Kernel 2: per-question precompute (r19 form, 4-accumulator rowdot).
// ---------------------------------------------------------------------------
__global__ void __launch_bounds__(192) k_perq(
    const float* __restrict__ E_q, const float* __restrict__ W_ih,
    const float* __restrict__ qd_W1, const float* __restrict__ qd_b1,
    const float* __restrict__ qd_W2, const float* __restrict__ qd_b2,
    const float* __restrict__ dc_W1, const float* __restrict__ dc_b1,
    const float* __restrict__ dc_W2, const float* __restrict__ dc_b2,
    const int* __restrict__ q2c, const int* __restrict__ q2cm,
    const float* __restrict__ T_c,
    float* __restrict__ Xq, float* __restrict__ disc,
    float* __restrict__ qds, float* __restrict__ wdk)
{
    __shared__ float s_wbuf[192 * 66];
    __shared__ float s_qe[QPB][64];
    __shared__ float s_wq[QPB][4];
    __shared__ int   s_cq[QPB][4];
    __shared__ float s_hidw[3][136];

    const int tid = threadIdx.x, w = tid >> 6, l = tid & 63;
    const int q0 = blockIdx.x * QPB;

    for (int i = tid; i < 132 * 64; i += 192)
        s_wbuf[(i >> 6) * 66 + (i & 63)] = qd_W1[i];
    for (int i = tid; i < 32 * 64; i += 192)
        s_wbuf[(132 + (i >> 6)) * 66 + (i & 63)] = dc_W1[i];
    for (int i = tid; i < QPB * 64; i += 192) {
        int qq = i >> 6, q = q0 + qq;
        s_qe[qq][i & 63] = E_q[(q < QN ? q : 0) * 64 + (i & 63)];
    }
    __syncthreads();

    for (int qq = w; qq < QPB; qq += 3) {
        int q = q0 + qq;
        bool valid = q < QN;
        int qc = valid ? q : 0;
        int cc[4], mm[4];
        #pragma unroll
        for (int k = 0; k < 4; k++) { cc[k] = q2c[qc * 4 + k]; mm[k] = q2cm[qc * 4 + k]; }

        float qe[64];
        #pragma unroll
        for (int k4 = 0; k4 < 16; k4++) {
            float4 v = *(const float4*)(&s_qe[qq][k4 * 4]);
            qe[4 * k4] = v.x; qe[4 * k4 + 1] = v.y; qe[4 * k4 + 2] = v.z; qe[4 * k4 + 3] = v.w;
        }

        auto rowdot = [&](int r) {
            const float* wr = s_wbuf + r * 66;
            float a0 = 0.f, a1 = 0.f, a2 = 0.f, a3 = 0.f;
            #pragma unroll
            for (int jj = 0; jj < 32; jj += 4) {
                float2 w0 = *(const float2*)(wr + 2 * jj);
                float2 w1 = *(const float2*)(wr + 2 * jj + 2);
                float2 w2 = *(const float2*)(wr + 2 * jj + 4);
                float2 w3 = *(const float2*)(wr + 2 * jj + 6);
                a0 += w0.x * qe[2 * jj]     + w0.y * qe[2 * jj + 1];
                a1 += w1.x * qe[2 * jj + 2] + w1.y * qe[2 * jj + 3];
                a2 += w2.x * qe[2 * jj + 4] + w2.y * qe[2 * jj + 5];
                a3 += w3.x * qe[2 * jj + 6] + w3.y * qe[2 * jj + 7];
            }
            return (a0 + a1) + (a2 + a3);
        };

        s_hidw[w][l]      = fmaxf(rowdot(l)      + qd_b1[l],      0.f);
        s_hidw[w][64 + l] = fmaxf(rowdot(64 + l) + qd_b1[64 + l], 0.f);
        if (l < 4)
            s_hidw[w][128 + l] = fmaxf(rowdot(128 + l) + qd_b1[128 + l], 0.f);
        float dch = 0.f;
        if (l < 32) dch = fmaxf(rowdot(132 + l) + dc_b1[l], 0.f);

        int g = l >> 4, li = l & 15;
        int c = cc[g];
        float acc = 0.f;
        #pragma unroll
        for (int i = 0; i < 9; i++) {
            int m = li + 16 * i;
            if (m < 132) acc += qd_W2[c * 132 + m] * s_hidw[w][m];
        }
        acc += __shfl_xor(acc, 1); acc += __shfl_xor(acc, 2);
        acc += __shfl_xor(acc, 4); acc += __shfl_xor(acc, 8);
        float r0 = __shfl(acc, 0), r1 = __shfl(acc, 16);
        float r2 = __shfl(acc, 32), r3 = __shfl(acc, 48);

        float raw[4] = { sigm(r0 + qd_b2[cc[0]]), sigm(r1 + qd_b2[cc[1]]),
                         sigm(r2 + qd_b2[cc[2]]), sigm(r3 + qd_b2[cc[3]]) };
        float rel[4];
        #pragma unroll
        for (int k = 0; k < 4; k++) rel[k] = raw[k] * (float)mm[k];
        float sr = rel[0] + rel[1] + rel[2] + rel[3] + 1e-6f;

        float qsum = 0.f, wdv[4];
        #pragma unroll
        for (int k = 0; k < 4; k++) {
            float wd = 0.f;
            if (mm[k]) {
                bool dup = false;
                for (int jj = 0; jj < k; jj++)
                    if (mm[jj] && cc[jj] == cc[k]) dup = true;
                if (!dup) { wd = 1.f; qsum += raw[k]; }
            }
            wdv[k] = wd;
        }
        if (l < 4) { s_wq[qq][l] = rel[l] / sr; s_cq[qq][l] = cc[l]; }
        if (valid) {
            if (l < 4) wdk[q * 4 + l] = wdv[l];
            if (l == 0) qds[q] = qsum;
        }

        float dv = (l < 32) ? dch * dc_W2[l] : 0.f;
        dv += __shfl_xor(dv, 1);  dv += __shfl_xor(dv, 2);
        dv += __shfl_xor(dv, 4);  dv += __shfl_xor(dv, 8);
        dv += __shfl_xor(dv, 16);
        if (valid && l == 0) disc[q] = sigm(dv + dc_b2[0]) * 10.f;
    }

    __syncthreads();
    for (int i = tid; i < 192 * 64; i += 192) {
        int r = i >> 6, k = i & 63;
        s_wbuf[r * 66 + k] = W_ih[r * 320 + k];
    }
    __syncthreads();

    for (int qq = w; qq < QPB; qq += 3) {
        int q = q0 + qq;
        if (q >= QN) continue;

        float qe[64];
        #pragma unroll
        for (int k4 = 0; k4 < 16; k4++) {
            float4 v = *(const float4*)(&s_qe[qq][k4 * 4]);
            qe[4 * k4] = v.x; qe[4 * k4 + 1] = v.y; qe[4 * k4 + 2] = v.z; qe[4 * k4 + 3] = v.w;
        }
        float wq[4]; int cq[4];
        #pragma unroll
        for (int k = 0; k < 4; k++) { wq[k] = s_wq[qq][k]; cq[k] = s_cq[qq][k]; }

        #pragma unroll
        for (int rr = 0; rr < 3; rr++) {
            int row = rr * 64 + l;
            const float* wr = s_wbuf + row * 66;
            float a0 = 0.f, a1 = 0.f, a2 = 0.f, a3 = 0.f;
            #pragma unroll
            for (int jj = 0; jj < 32; jj += 4) {
                float2 w0 = *(const float2*)(wr + 2 * jj);
                float2 w1 = *(const float2*)(wr + 2 * jj + 2);
                float2 w2 = *(const float2*)(wr + 2 * jj + 4);
                float2 w3 = *(const float2*)(wr + 2 * jj + 6);
                a0 += w0.x * qe[2 * jj]     + w0.y * qe[2 * jj + 1];
                a1 += w1.x * qe[2 * jj + 2] + w1.y * qe[2 * jj + 3];
                a2 += w2.x * qe[2 * jj + 4] + w2.y * qe[2 * jj + 5];
                a3 += w3.x * qe[2 * jj + 6] + w3.y * qe[2 * jj + 7];
            }
            float a = (a0 + a1) + (a2 + a3);
            #pragma unroll
            for (int k = 0; k < 4; k++) a += wq[k] * T_c[cq[k] * 192 + row];
            Xq[q * 256 + l * 4 + rr] = a;
        }
    }
}

// ---------------------------------------------------------------------------
// Kernel 3 v22: FUSED; scan weights IN LDS ([k][lane], conflict-free) so the
// allocator has nothing to demote -> no residency/occupancy fight. VGPR drops
// to ~80 -> waves_per_eu(1,2) gives 2 blocks/CU (single pass) AND a 4-wave
// readout (8 waves/CU during readout -> latency hidden, r18-proven).
// h-history stored as packed f16 pairs s_lat_h[200][33] (pad-33 kills the
// readout bank conflict; total LDS 76.4KB <= 80KB for 2 blocks/CU).
// ---------------------------------------------------------------------------
__global__ void
__launch_bounds__(256)
__attribute__((amdgpu_waves_per_eu(1, 2)))
k_gru(
    const float* __restrict__ W_hh, const float* __restrict__ b_hh,
    const float* __restrict__ XqI, const float* __restrict__ TitI, const float* __restrict__ TutI,
    const float* __restrict__ TnhI, const float* __restrict__ TnaI,
    const float* __restrict__ b0, const float* __restrict__ vc,
    const int* __restrict__ qseq, const int* __restrict__ cseq, const int* __restrict__ itseq,
    const int* __restrict__ utseq, const int* __restrict__ nhseq, const int* __restrict__ naseq,
    const unsigned* __restrict__ w1h, const float* __restrict__ la_b1,
    const unsigned* __restrict__ w2h, const float* __restrict__ la_b2,
    const int* __restrict__ q2c,
    const float* __restrict__ disc, const float* __restrict__ qds,
    const float* __restrict__ wdk, float* __restrict__ out)
{
    const int tid = threadIdx.x, b = blockIdx.x;
    const int wave = tid >> 6, j = tid & 63;
    const int j4 = 4 * j;

    __shared__ float s_gb[4][5][64][4];      // 20KB gather slots
    __shared__ int s_ix[6 * TT];             // 4.8KB indices
    __shared__ unsigned s_hp[32];            // packed h (current)
    __shared__ unsigned s_wl[96 * 64];       // 24.6KB packed W_hh, [k][lane]
    __shared__ unsigned s_lat_h[TT][33];     // 26.4KB packed h history (pad-33)

    const int base = b * TT;
    for (int i = tid; i < TT; i += 256) {
        s_ix[i]          = qseq[base + i];
        s_ix[TT + i]     = cseq[base + i];
        s_ix[2 * TT + i] = itseq[base + i];
        s_ix[3 * TT + i] = utseq[base + i];
        s_ix[4 * TT + i] = nhseq[base + i];
        s_ix[5 * TT + i] = naseq[base + i];
    }
    // cooperative pack of W_hh into LDS: s_wl[k*64 + lane], k = gate*32 + kk
    for (int i = tid; i < 96 * 64; i += 256) {
        int k = i >> 6, jj = i & 63;
        int gate = k >> 5, kk = k & 31;
        const float* src = W_hh + (gate * 64 + jj) * 64 + 2 * kk;
        s_wl[i] = packh_rtne(src[0], src[1]);
    }
    if (tid < 32) s_hp[tid] = 0u;
    __syncthreads();

    if (wave == 0) {
        const float bhr = b_hh[j], bhz = b_hh[64 + j], bhn = b_hh[128 + j];
        const float b0r = b0[j],   b0z = b0[64 + j],   b0n = b0[128 + j];
        const float vcr = vc[j],   vcz = vc[64 + j],   vcn = vc[128 + j];

        float hj = 0.f;
        float cA, cB, cC, cD;

#define GISSUE(S, CCV, tt) { \
        int q_ = s_ix[tt], c_ = s_ix[TT + tt], it_ = s_ix[2 * TT + tt]; \
        int ut_ = s_ix[3 * TT + tt], nh_ = s_ix[4 * TT + tt], na_ = s_ix[5 * TT + tt]; \
        CCV = (float)c_; \
        glds16(XqI  + q_  * 256 + j4, &s_gb[S][0][0][0]); \
        glds16(TitI + it_ * 256 + j4, &s_gb[S][1][0][0]); \
        glds16(TutI + ut_ * 256 + j4, &s_gb[S][2][0][0]); \
        glds16(TnhI + nh_ * 256 + j4, &s_gb[S][3][0][0]); \
        glds16(TnaI + na_ * 256 + j4, &s_gb[S][4][0][0]); \
    }

#define STEP(S, CCV, tcur, WN, REF) { \
        asm volatile("s_waitcnt vmcnt(" WN ")" ::: "memory"); \
        f4v g0 = *(const f4v*)&s_gb[S][0][j][0]; \
        f4v g1 = *(const f4v*)&s_gb[S][1][j][0]; \
        f4v g2 = *(const f4v*)&s_gb[S][2][j][0]; \
        f4v g3 = *(const f4v*)&s_gb[S][3][j][0]; \
        f4v g4 = *(const f4v*)&s_gb[S][4][j][0]; \
        asm volatile("s_waitcnt lgkmcnt(0)" ::: "memory"); \
        float xr = b0r + CCV * vcr + (((g0.x + g1.x) + (g2.x + g3.x)) + g4.x); \
        float xz = b0z + CCV * vcz + (((g0.y + g1.y) + (g2.y + g3.y)) + g4.y); \
        float xn = b0n + CCV * vcn + (((g0.z + g1.z) + (g2.z + g3.z)) + g4.z); \
        if (REF) GISSUE(S, CCV, (tcur) + 4); \
        float ar0 = 0.f, ar1 = 0.f, ar2 = 0.f, ar3 = 0.f; \
        float az0 = 0.f, az1 = 0.f, az2 = 0.f, az3 = 0.f; \
        float an0 = 0.f, an1 = 0.f, an2 = 0.f, an3 = 0.f; \
        const uint4* hp4 = (const uint4*)s_hp; \
        _Pragma("unroll") \
        for (int k4 = 0; k4 < 8; k4++) { \
            uint4 hh = hp4[k4]; \
            ar0 = fdot2u(s_wl[(4 * k4 + 0) * 64 + j],        hh.x, ar0); \
            ar1 = fdot2u(s_wl[(4 * k4 + 1) * 64 + j],        hh.y, ar1); \
            ar2 = fdot2u(s_wl[(4 * k4 + 2) * 64 + j],        hh.z, ar2); \
            ar3 = fdot2u(s_wl[(4 * k4 + 3) * 64 + j],        hh.w, ar3); \
            az0 = fdot2u(s_wl[(32 + 4 * k4 + 0) * 64 + j],   hh.x, az0); \
            az1 = fdot2u(s_wl[(32 + 4 * k4 + 1) * 64 + j],   hh.y, az1); \
            az2 = fdot2u(s_wl[(32 + 4 * k4 + 2) * 64 + j],   hh.z, az2); \
            az3 = fdot2u(s_wl[(32 + 4 * k4 + 3) * 64 + j],   hh.w, az3); \
            an0 = fdot2u(s_wl[(64 + 4 * k4 + 0) * 64 + j],   hh.x, an0); \
            an1 = fdot2u(s_wl[(64 + 4 * k4 + 1) * 64 + j],   hh.y, an1); \
            an2 = fdot2u(s_wl[(64 + 4 * k4 + 2) * 64 + j],   hh.z, an2); \
            an3 = fdot2u(s_wl[(64 + 4 * k4 + 3) * 64 + j],   hh.w, an3); \
        } \
        float ar = ((ar0 + ar1) + (ar2 + ar3)) + bhr; \
        float az = ((az0 + az1) + (az2 + az3)) + bhz; \
        float an = ((an0 + an1) + (an2 + an3)) + bhn; \
        float r = sigm(xr + ar); \
        float z = sigm(xz + az); \
        float n = tanh_fast(xn + r * an); \
        hj = (1.f - z) * n + z * hj; \
        float hnb = __shfl_xor(hj, 1); \
        unsigned pk = (j & 1) ? packh_rtne(hnb, hj) : packh_rtne(hj, hnb); \
        if (!(j & 1)) { s_hp[j >> 1] = pk; s_lat_h[tcur][j >> 1] = pk; } \
    }

        GISSUE(0, cA, 0);
        GISSUE(1, cB, 1);
        GISSUE(2, cC, 2);
        GISSUE(3, cD, 3);

        STEP(0, cA, 0, "15", 1);
        STEP(1, cB, 1, "15", 1);
        STEP(2, cC, 2, "15", 1);
        STEP(3, cD, 3, "15", 1);

        for (int t = 4; t <= TT - 8; t += 4) {
            STEP(0, cA, t,     "15", 1);
            STEP(1, cB, t + 1, "15", 1);
            STEP(2, cC, t + 2, "15", 1);
            STEP(3, cD, t + 3, "15", 1);
        }
        STEP(0, cA, TT - 4, "15", 0);
        STEP(1, cB, TT - 3, "10", 0);
        STEP(2, cC, TT - 2, "5",  0);
        STEP(3, cD, TT - 1, "0",  0);
#undef STEP
#undef GISSUE
    }
    __syncthreads();

    // ---- readout phase: thread t handles token t (199 tokens, 4 waves) ----
    if (tid < TT - 1) {
        const int t = tid;
        unsigned L[32];
        {
            #pragma unroll
            for (int kk = 0; kk < 32; kk++) L[kk] = s_lat_h[t][kk];
        }

        unsigned hidpk[66];
        float hprev = 0.f;
        #pragma unroll
        for (int m = 0; m < 132; m++) {
            const unsigned* w1r = w1h + m * 32;
            float a0 = 0.f, a1 = 0.f, a2 = 0.f, a3 = 0.f;
            #pragma unroll
            for (int k = 0; k < 32; k += 4) {
                a0 = fdot2u(w1r[k],     L[k],     a0);
                a1 = fdot2u(w1r[k + 1], L[k + 1], a1);
                a2 = fdot2u(w1r[k + 2], L[k + 2], a2);
                a3 = fdot2u(w1r[k + 3], L[k + 3], a3);
            }
            float hm = fmaxf(((a0 + a1) + (a2 + a3)) + la_b1[m], 0.f);
            if (m & 1) hidpk[m >> 1] = packh_rtne(hprev, hm);
            else hprev = hm;
        }

        int q = s_ix[t + 1];
        float u[4];
        #pragma unroll
        for (int kc = 0; kc < 4; kc++) {
            int c = q2c[q * 4 + kc];
            const unsigned* w2r = w2h + c * 68;
            float u0 = 0.f, u1 = 0.f;
            #pragma unroll
            for (int k = 0; k < 66; k += 2) {
                u0 = fdot2u(w2r[k],     hidpk[k],     u0);
                u1 = fdot2u(w2r[k + 1], hidpk[k + 1], u1);
            }
            u[kc] = u0 + u1 + la_b2[c];
        }

        float us = 0.f;
        #pragma unroll
        for (int kc = 0; kc < 4; kc++) us += wdk[q * 4 + kc] * sigm(u[kc]);
        float qs = qds[q];
        float y = disc[q] * (us - qs) / (qs + 1e-6f);
        out[(size_t)b * (TT - 1) + t] = sigm(y);
    }
}

// ---------------------------------------------------------------------------
extern "C" void kernel_launch(void* const* d_in, const int* in_sizes, int n_in,
                              void* d_out, int out_size, void* d_ws, size_t ws_size,
                              hipStream_t stream)
{
    const float* E_q    = (const float*)d_in[0];
    const float* E_c    = (const float*)d_in[1];
    const float* E_it   = (const float*)d_in[2];
    const float* E_ut   = (const float*)d_in[3];
    const float* E_nh   = (const float*)d_in[4];
    const float* W_fuse = (const float*)d_in[5];
    const float* b_fuse = (const float*)d_in[6];
    const float* W_ih   = (const float*)d_in[7];
    const float* b_ih   = (const float*)d_in[8];
    const float* W_hh   = (const float*)d_in[9];
    const float* b_hh   = (const float*)d_in[10];
    const float* qd_W1  = (const float*)d_in[11];
    const float* qd_b1  = (const float*)d_in[12];
    const float* qd_W2  = (const float*)d_in[13];
    const float* qd_b2  = (const float*)d_in[14];
    const float* la_W1  = (const float*)d_in[15];
    const float* la_b1  = (const float*)d_in[16];
    const float* la_W2  = (const float*)d_in[17];
    const float* la_b2  = (const float*)d_in[18];
    const float* dc_W1  = (const float*)d_in[19];
    const float* dc_b1  = (const float*)d_in[20];
    const float* dc_W2  = (const float*)d_in[21];
    const float* dc_b2  = (const float*)d_in[22];

    int off = (in_sizes[23] == QN * 200) ? 1 : 0;
    const int* qseq  = (const int*)d_in[23 + off];
    const int* cseq  = (const int*)d_in[24 + off];
    const int* itseq = (const int*)d_in[25 + off];
    const int* utseq = (const int*)d_in[26 + off];
    const int* nhseq = (const int*)d_in[27 + off];
    const int* naseq = (const int*)d_in[28 + off];
    const int* q2c   = (const int*)d_in[29 + off];
    const int* q2cm  = (const int*)d_in[30 + off];

    float* ws = (float*)d_ws;
    size_t o = 0;
    float* T_c  = ws + o; o += (size_t)201 * 192;
    float* Tit  = ws + o; o += (size_t)101 * 256;
    float* Tut  = ws + o; o += (size_t)101 * 256;
    float* Tnh  = ws + o; o += (size_t)101 * 256;
    float* Tna  = ws + o; o += (size_t)101 * 256;
    float* b0   = ws + o; o += 192;
    float* vc   = ws + o; o += 192;
    float* Xq   = ws + o; o += (size_t)QN * 256;
    float* disc = ws + o; o += QN;
    float* qds  = ws + o; o += QN;
    float* wdk  = ws + o; o += (size_t)QN * 4;
    unsigned* w1h = (unsigned*)(ws + o); o += (size_t)132 * 32;
    unsigned* w2h = (unsigned*)(ws + o); o += (size_t)200 * 68;

    float* outp = (float*)d_out;

    k_tables<<<699, 192, 0, stream>>>(E_c, E_it, E_ut, E_nh, W_fuse, b_fuse, W_ih, b_ih,
                                      la_W1, la_W2,
                                      T_c, Tit, Tut, Tnh, Tna, b0, vc, w1h, w2h);
    k_perq<<<(QN + QPB - 1) / QPB, 192, 0, stream>>>(E_q, W_ih, qd_W1, qd_b1, qd_W2, qd_b2,
                                                     dc_W1, dc_b1, dc_W2, dc_b2, q2c, q2cm, T_c,
                                                     Xq, disc, qds, wdk);
    k_gru<<<BB, 256, 0, stream>>>(W_hh, b_hh, Xq, Tit, Tut, Tnh, Tna, b0, vc,
                                  qseq, cseq, itseq, utseq, nhseq, naseq,
                                  w1h, la_b1, w2h, la_b2, q2c, disc, qds, wdk, outp);
}

// Round 23
// 297.067 us; speedup vs baseline: 1.4847x; 1.3264x over previous
//
#include <hip/hip_runtime.h>
#include <hip/hip_fp16.h>

// Problem constants
constexpr int QN  = 10001;   // questions (Q+1)
constexpr int BB  = 512;     // batch
constexpr int TT  = 200;     // seq len
constexpr int QPB = 32;      // questions per block in k_perq

__device__ __forceinline__ float sigm(float x) { return 1.f / (1.f + __expf(-x)); }
__device__ __forceinline__ float tanh_fast(float x) { return 1.f - 2.f / (1.f + __expf(2.f * x)); }

__device__ __forceinline__ unsigned packh_rtne(float lo, float hi) {
    return ((unsigned)__half_as_ushort(__float2half(hi)) << 16) |
            (unsigned)__half_as_ushort(__float2half(lo));
}

typedef _Float16 half2_t __attribute__((ext_vector_type(2)));
typedef float f4v __attribute__((ext_vector_type(4)));
__device__ __forceinline__ half2_t u2h(unsigned u) {
    union { unsigned u; half2_t h; } x; x.u = u; return x.h;
}

#if __has_builtin(__builtin_amdgcn_fdot2)
__device__ __forceinline__ float fdot2u(unsigned wu, unsigned hu, float acc) {
    return __builtin_amdgcn_fdot2(u2h(wu), u2h(hu), acc, false);
}
#else
__device__ __forceinline__ float fdot2u(unsigned wu, unsigned hu, float acc) {
    float wlo = __half2float(__ushort_as_half((unsigned short)(wu & 0xffffu)));
    float whi = __half2float(__ushort_as_half((unsigned short)(wu >> 16)));
    float hlo = __half2float(__ushort_as_half((unsigned short)(hu & 0xffffu)));
    float hhi = __half2float(__ushort_as_half((unsigned short)(hu >> 16)));
    return acc + wlo * hlo + whi * hhi;
}
#endif

// async global->LDS, 16B per lane
typedef const __attribute__((address_space(1))) void cgv_t;
typedef __attribute__((address_space(3))) void lv_t;
__device__ __forceinline__ void glds16(const float* g, float* l) {
    __builtin_amdgcn_global_load_lds((cgv_t*)g, (lv_t*)l, 16, 0, 0);
}

// ---------------------------------------------------------------------------
// Kernel 1: precomputed tables (r18 form).
// ---------------------------------------------------------------------------
__global__ void k_tables(const float* __restrict__ E_c, const float* __restrict__ E_it,
                         const float* __restrict__ E_ut, const float* __restrict__ E_nh,
                         const float* __restrict__ W_fuse, const float* __restrict__ b_fuse,
                         const float* __restrict__ W_ih, const float* __restrict__ b_ih,
                         const float* __restrict__ la_W1, const float* __restrict__ la_W2,
                         float* __restrict__ T_c, float* __restrict__ T_it,
                         float* __restrict__ T_ut, float* __restrict__ T_nh, float* __restrict__ T_na,
                         float* __restrict__ bias0, float* __restrict__ Vcorr,
                         unsigned* __restrict__ w1h, unsigned* __restrict__ w2h)
{
    int blk = blockIdx.x, j = threadIdx.x; // 192 threads
    __shared__ float s_e[64];
    __shared__ float s_t[64];
    const int ilv4 = (j & 63) * 4 + (j >> 6);

    if (blk < 201) {
        if (j < 64) s_e[j] = E_c[blk * 64 + j];
        __syncthreads();
        float a = 0.f;
        #pragma unroll
        for (int k = 0; k < 64; k++) a += W_ih[j * 320 + 64 + k] * s_e[k];
        T_c[blk * 192 + j] = a;
    } else if (blk < 302) {
        int r = blk - 201;
        if (j < 64) s_e[j] = E_it[r * 64 + j];
        __syncthreads();
        float a = 0.f;
        #pragma unroll
        for (int k = 0; k < 64; k++) a += W_ih[j * 320 + 192 + k] * s_e[k];
        T_it[r * 256 + ilv4] = a;
    } else if (blk < 605) {
        int which = (blk - 302) / 101;
        int r     = (blk - 302) % 101;
        const float* E = (which == 0) ? E_ut : E_nh;
        int fofs = which * 64;
        if (j < 64) s_e[j] = E[r * 64 + j];
        __syncthreads();
        if (j < 64) {
            float a = 0.f;
            #pragma unroll
            for (int d = 0; d < 64; d++) a += W_fuse[j * 192 + fofs + d] * s_e[d];
            s_t[j] = a;
        }
        __syncthreads();
        float a = 0.f;
        #pragma unroll
        for (int e = 0; e < 64; e++) a += W_ih[j * 320 + 256 + e] * s_t[e];
        float* outp = (which == 0) ? T_ut : ((which == 1) ? T_nh : T_na);
        outp[r * 256 + ilv4] = a;
    } else if (blk == 605) {
        float a = b_ih[j];
        #pragma unroll
        for (int e = 0; e < 64; e++) a += W_ih[j * 320 + 256 + e] * b_fuse[e];
        bias0[j] = a;
        float v = 0.f;
        #pragma unroll
        for (int k = 0; k < 64; k++) v += W_ih[j * 320 + 128 + k];
        Vcorr[j] = v;
    } else if (blk < 628) {
        int i = (blk - 606) * 192 + j;      // 132*32 = 4224 exact
        int m = i >> 5, k = i & 31;
        w1h[i] = packh_rtne(la_W1[m * 64 + 2 * k], la_W1[m * 64 + 2 * k + 1]);
    } else {
        int i = (blk - 628) * 192 + j;
        if (i < 200 * 68) {
            int c = i / 68, k = i - c * 68;
            w2h[i] = (k < 66) ? packh_rtne(la_W2[c * 132 + 2 * k], la_W2[c * 132 + 2 * k + 1]) : 0u;
        }
    }
}

// ---------------------------------------------------------------------------
// Kernel 2: per-question precompute (r19 form, 4-accumulator rowdot).
// ---------------------------------------------------------------------------
__global__ void __launch_bounds__(192) k_perq(
    const float* __restrict__ E_q, const float* __restrict__ W_ih,
    const float* __restrict__ qd_W1, const float* __restrict__ qd_b1,
    const float* __restrict__ qd_W2, const float* __restrict__ qd_b2,
    const float* __restrict__ dc_W1, const float* __restrict__ dc_b1,
    const float* __restrict__ dc_W2, const float* __restrict__ dc_b2,
    const int* __restrict__ q2c, const int* __restrict__ q2cm,
    const float* __restrict__ T_c,
    float* __restrict__ Xq, float* __restrict__ disc,
    float* __restrict__ qds, float* __restrict__ wdk)
{
    __shared__ float s_wbuf[192 * 66];
    __shared__ float s_qe[QPB][64];
    __shared__ float s_wq[QPB][4];
    __shared__ int   s_cq[QPB][4];
    __shared__ float s_hidw[3][136];

    const int tid = threadIdx.x, w = tid >> 6, l = tid & 63;
    const int q0 = blockIdx.x * QPB;

    for (int i = tid; i < 132 * 64; i += 192)
        s_wbuf[(i >> 6) * 66 + (i & 63)] = qd_W1[i];
    for (int i = tid; i < 32 * 64; i += 192)
        s_wbuf[(132 + (i >> 6)) * 66 + (i & 63)] = dc_W1[i];
    for (int i = tid; i < QPB * 64; i += 192) {
        int qq = i >> 6, q = q0 + qq;
        s_qe[qq][i & 63] = E_q[(q < QN ? q : 0) * 64 + (i & 63)];
    }
    __syncthreads();

    for (int qq = w; qq < QPB; qq += 3) {
        int q = q0 + qq;
        bool valid = q < QN;
        int qc = valid ? q : 0;
        int cc[4], mm[4];
        #pragma unroll
        for (int k = 0; k < 4; k++) { cc[k] = q2c[qc * 4 + k]; mm[k] = q2cm[qc * 4 + k]; }

        float qe[64];
        #pragma unroll
        for (int k4 = 0; k4 < 16; k4++) {
            float4 v = *(const float4*)(&s_qe[qq][k4 * 4]);
            qe[4 * k4] = v.x; qe[4 * k4 + 1] = v.y; qe[4 * k4 + 2] = v.z; qe[4 * k4 + 3] = v.w;
        }

        auto rowdot = [&](int r) {
            const float* wr = s_wbuf + r * 66;
            float a0 = 0.f, a1 = 0.f, a2 = 0.f, a3 = 0.f;
            #pragma unroll
            for (int jj = 0; jj < 32; jj += 4) {
                float2 w0 = *(const float2*)(wr + 2 * jj);
                float2 w1 = *(const float2*)(wr + 2 * jj + 2);
                float2 w2 = *(const float2*)(wr + 2 * jj + 4);
                float2 w3 = *(const float2*)(wr + 2 * jj + 6);
                a0 += w0.x * qe[2 * jj]     + w0.y * qe[2 * jj + 1];
                a1 += w1.x * qe[2 * jj + 2] + w1.y * qe[2 * jj + 3];
                a2 += w2.x * qe[2 * jj + 4] + w2.y * qe[2 * jj + 5];
                a3 += w3.x * qe[2 * jj + 6] + w3.y * qe[2 * jj + 7];
            }
            return (a0 + a1) + (a2 + a3);
        };

        s_hidw[w][l]      = fmaxf(rowdot(l)      + qd_b1[l],      0.f);
        s_hidw[w][64 + l] = fmaxf(rowdot(64 + l) + qd_b1[64 + l], 0.f);
        if (l < 4)
            s_hidw[w][128 + l] = fmaxf(rowdot(128 + l) + qd_b1[128 + l], 0.f);
        float dch = 0.f;
        if (l < 32) dch = fmaxf(rowdot(132 + l) + dc_b1[l], 0.f);

        int g = l >> 4, li = l & 15;
        int c = cc[g];
        float acc = 0.f;
        #pragma unroll
        for (int i = 0; i < 9; i++) {
            int m = li + 16 * i;
            if (m < 132) acc += qd_W2[c * 132 + m] * s_hidw[w][m];
        }
        acc += __shfl_xor(acc, 1); acc += __shfl_xor(acc, 2);
        acc += __shfl_xor(acc, 4); acc += __shfl_xor(acc, 8);
        float r0 = __shfl(acc, 0), r1 = __shfl(acc, 16);
        float r2 = __shfl(acc, 32), r3 = __shfl(acc, 48);

        float raw[4] = { sigm(r0 + qd_b2[cc[0]]), sigm(r1 + qd_b2[cc[1]]),
                         sigm(r2 + qd_b2[cc[2]]), sigm(r3 + qd_b2[cc[3]]) };
        float rel[4];
        #pragma unroll
        for (int k = 0; k < 4; k++) rel[k] = raw[k] * (float)mm[k];
        float sr = rel[0] + rel[1] + rel[2] + rel[3] + 1e-6f;

        float qsum = 0.f, wdv[4];
        #pragma unroll
        for (int k = 0; k < 4; k++) {
            float wd = 0.f;
            if (mm[k]) {
                bool dup = false;
                for (int jj = 0; jj < k; jj++)
                    if (mm[jj] && cc[jj] == cc[k]) dup = true;
                if (!dup) { wd = 1.f; qsum += raw[k]; }
            }
            wdv[k] = wd;
        }
        if (l < 4) { s_wq[qq][l] = rel[l] / sr; s_cq[qq][l] = cc[l]; }
        if (valid) {
            if (l < 4) wdk[q * 4 + l] = wdv[l];
            if (l == 0) qds[q] = qsum;
        }

        float dv = (l < 32) ? dch * dc_W2[l] : 0.f;
        dv += __shfl_xor(dv, 1);  dv += __shfl_xor(dv, 2);
        dv += __shfl_xor(dv, 4);  dv += __shfl_xor(dv, 8);
        dv += __shfl_xor(dv, 16);
        if (valid && l == 0) disc[q] = sigm(dv + dc_b2[0]) * 10.f;
    }

    __syncthreads();
    for (int i = tid; i < 192 * 64; i += 192) {
        int r = i >> 6, k = i & 63;
        s_wbuf[r * 66 + k] = W_ih[r * 320 + k];
    }
    __syncthreads();

    for (int qq = w; qq < QPB; qq += 3) {
        int q = q0 + qq;
        if (q >= QN) continue;

        float qe[64];
        #pragma unroll
        for (int k4 = 0; k4 < 16; k4++) {
            float4 v = *(const float4*)(&s_qe[qq][k4 * 4]);
            qe[4 * k4] = v.x; qe[4 * k4 + 1] = v.y; qe[4 * k4 + 2] = v.z; qe[4 * k4 + 3] = v.w;
        }
        float wq[4]; int cq[4];
        #pragma unroll
        for (int k = 0; k < 4; k++) { wq[k] = s_wq[qq][k]; cq[k] = s_cq[qq][k]; }

        #pragma unroll
        for (int rr = 0; rr < 3; rr++) {
            int row = rr * 64 + l;
            const float* wr = s_wbuf + row * 66;
            float a0 = 0.f, a1 = 0.f, a2 = 0.f, a3 = 0.f;
            #pragma unroll
            for (int jj = 0; jj < 32; jj += 4) {
                float2 w0 = *(const float2*)(wr + 2 * jj);
                float2 w1 = *(const float2*)(wr + 2 * jj + 2);
                float2 w2 = *(const float2*)(wr + 2 * jj + 4);
                float2 w3 = *(const float2*)(wr + 2 * jj + 6);
                a0 += w0.x * qe[2 * jj]     + w0.y * qe[2 * jj + 1];
                a1 += w1.x * qe[2 * jj + 2] + w1.y * qe[2 * jj + 3];
                a2 += w2.x * qe[2 * jj + 4] + w2.y * qe[2 * jj + 5];
                a3 += w3.x * qe[2 * jj + 6] + w3.y * qe[2 * jj + 7];
            }
            float a = (a0 + a1) + (a2 + a3);
            #pragma unroll
            for (int k = 0; k < 4; k++) a += wq[k] * T_c[cq[k] * 192 + row];
            Xq[q * 256 + l * 4 + rr] = a;
        }
    }
}

// ---------------------------------------------------------------------------
// Kernel 3 v23: SCAN ONLY, r13-proven config (64 thr, waves_per_eu(1,1),
// reg-resident packed weights VGPR 132, glds16 4-slot pipeline). Only change
// vs r13: latent written PACKED f16 (half traffic; even lanes store pk).
// ---------------------------------------------------------------------------
__global__ void
__launch_bounds__(64)
__attribute__((amdgpu_waves_per_eu(1, 1)))
k_gru(
    const float* __restrict__ W_hh, const float* __restrict__ b_hh,
    const float* __restrict__ XqI, const float* __restrict__ TitI, const float* __restrict__ TutI,
    const float* __restrict__ TnhI, const float* __restrict__ TnaI,
    const float* __restrict__ b0, const float* __restrict__ vc,
    const int* __restrict__ qseq, const int* __restrict__ cseq, const int* __restrict__ itseq,
    const int* __restrict__ utseq, const int* __restrict__ nhseq, const int* __restrict__ naseq,
    unsigned* __restrict__ lath)
{
    const int j = threadIdx.x, b = blockIdx.x;
    const int j4 = 4 * j;

    __shared__ float s_gb[4][5][64][4];   // 20KB gather slots
    __shared__ int s_ix[6 * TT];          // 4.8KB indices
    __shared__ unsigned s_hp[32];         // packed h

    const int base = b * TT;
    for (int i = j; i < TT; i += 64) {
        s_ix[i]          = qseq[base + i];
        s_ix[TT + i]     = cseq[base + i];
        s_ix[2 * TT + i] = itseq[base + i];
        s_ix[3 * TT + i] = utseq[base + i];
        s_ix[4 * TT + i] = nhseq[base + i];
        s_ix[5 * TT + i] = naseq[base + i];
    }

    unsigned wr[32], wz[32], wn[32];
    {
        const float4* p0 = (const float4*)(W_hh + j * 64);
        const float4* p1 = (const float4*)(W_hh + (64 + j) * 64);
        const float4* p2 = (const float4*)(W_hh + (128 + j) * 64);
        #pragma unroll
        for (int k = 0; k < 16; k++) {
            float4 a = p0[k], bq = p1[k], c = p2[k];
            wr[2 * k] = packh_rtne(a.x, a.y);  wr[2 * k + 1] = packh_rtne(a.z, a.w);
            wz[2 * k] = packh_rtne(bq.x, bq.y); wz[2 * k + 1] = packh_rtne(bq.z, bq.w);
            wn[2 * k] = packh_rtne(c.x, c.y);  wn[2 * k + 1] = packh_rtne(c.z, c.w);
        }
    }
    #pragma unroll
    for (int k = 0; k < 32; k++)
        asm volatile("" : "+v"(wr[k]), "+v"(wz[k]), "+v"(wn[k]));

    const float bhr = b_hh[j], bhz = b_hh[64 + j], bhn = b_hh[128 + j];
    const float b0r = b0[j],   b0z = b0[64 + j],   b0n = b0[128 + j];
    const float vcr = vc[j],   vcz = vc[64 + j],   vcn = vc[128 + j];

    if (j < 32) s_hp[j] = 0u;
    asm volatile("s_waitcnt lgkmcnt(0)" ::: "memory");

    float hj = 0.f;
    float cA, cB, cC, cD;
    unsigned* latb = lath + (size_t)base * 32;

#define GISSUE(S, CCV, tt) { \
        int q_ = s_ix[tt], c_ = s_ix[TT + tt], it_ = s_ix[2 * TT + tt]; \
        int ut_ = s_ix[3 * TT + tt], nh_ = s_ix[4 * TT + tt], na_ = s_ix[5 * TT + tt]; \
        CCV = (float)c_; \
        glds16(XqI  + q_  * 256 + j4, &s_gb[S][0][0][0]); \
        glds16(TitI + it_ * 256 + j4, &s_gb[S][1][0][0]); \
        glds16(TutI + ut_ * 256 + j4, &s_gb[S][2][0][0]); \
        glds16(TnhI + nh_ * 256 + j4, &s_gb[S][3][0][0]); \
        glds16(TnaI + na_ * 256 + j4, &s_gb[S][4][0][0]); \
    }

#define STEP(S, CCV, tcur, WN, REF) { \
        asm volatile("s_waitcnt vmcnt(" WN ")" ::: "memory"); \
        f4v g0 = *(const f4v*)&s_gb[S][0][j][0]; \
        f4v g1 = *(const f4v*)&s_gb[S][1][j][0]; \
        f4v g2 = *(const f4v*)&s_gb[S][2][j][0]; \
        f4v g3 = *(const f4v*)&s_gb[S][3][j][0]; \
        f4v g4 = *(const f4v*)&s_gb[S][4][j][0]; \
        asm volatile("s_waitcnt lgkmcnt(0)" ::: "memory"); \
        float xr = b0r + CCV * vcr + (((g0.x + g1.x) + (g2.x + g3.x)) + g4.x); \
        float xz = b0z + CCV * vcz + (((g0.y + g1.y) + (g2.y + g3.y)) + g4.y); \
        float xn = b0n + CCV * vcn + (((g0.z + g1.z) + (g2.z + g3.z)) + g4.z); \
        if (REF) GISSUE(S, CCV, (tcur) + 4); \
        float ar0 = 0.f, ar1 = 0.f, ar2 = 0.f, ar3 = 0.f; \
        float az0 = 0.f, az1 = 0.f, az2 = 0.f, az3 = 0.f; \
        float an0 = 0.f, an1 = 0.f, an2 = 0.f, an3 = 0.f; \
        const uint4* hp4 = (const uint4*)s_hp; \
        _Pragma("unroll") \
        for (int k4 = 0; k4 < 8; k4++) { \
            uint4 hh = hp4[k4]; \
            ar0 = fdot2u(wr[4 * k4 + 0], hh.x, ar0); \
            ar1 = fdot2u(wr[4 * k4 + 1], hh.y, ar1); \
            ar2 = fdot2u(wr[4 * k4 + 2], hh.z, ar2); \
            ar3 = fdot2u(wr[4 * k4 + 3], hh.w, ar3); \
            az0 = fdot2u(wz[4 * k4 + 0], hh.x, az0); \
            az1 = fdot2u(wz[4 * k4 + 1], hh.y, az1); \
            az2 = fdot2u(wz[4 * k4 + 2], hh.z, az2); \
            az3 = fdot2u(wz[4 * k4 + 3], hh.w, az3); \
            an0 = fdot2u(wn[4 * k4 + 0], hh.x, an0); \
            an1 = fdot2u(wn[4 * k4 + 1], hh.y, an1); \
            an2 = fdot2u(wn[4 * k4 + 2], hh.z, an2); \
            an3 = fdot2u(wn[4 * k4 + 3], hh.w, an3); \
        } \
        float ar = ((ar0 + ar1) + (ar2 + ar3)) + bhr; \
        float az = ((az0 + az1) + (az2 + az3)) + bhz; \
        float an = ((an0 + an1) + (an2 + an3)) + bhn; \
        float r = sigm(xr + ar); \
        float z = sigm(xz + az); \
        float n = tanh_fast(xn + r * an); \
        hj = (1.f - z) * n + z * hj; \
        float hnb = __shfl_xor(hj, 1); \
        unsigned pk = (j & 1) ? packh_rtne(hnb, hj) : packh_rtne(hj, hnb); \
        if (!(j & 1)) { s_hp[j >> 1] = pk; latb[(size_t)(tcur) * 32 + (j >> 1)] = pk; } \
    }

    GISSUE(0, cA, 0);
    GISSUE(1, cB, 1);
    GISSUE(2, cC, 2);
    GISSUE(3, cD, 3);

    STEP(0, cA, 0, "15", 1);
    STEP(1, cB, 1, "15", 1);
    STEP(2, cC, 2, "15", 1);
    STEP(3, cD, 3, "15", 1);

    for (int t = 4; t <= TT - 8; t += 4) {
        STEP(0, cA, t,     "15", 1);
        STEP(1, cB, t + 1, "15", 1);
        STEP(2, cC, t + 2, "15", 1);
        STEP(3, cD, t + 3, "15", 1);
    }
    STEP(0, cA, TT - 4, "15", 0);
    STEP(1, cB, TT - 3, "10", 0);
    STEP(2, cC, TT - 2, "5",  0);
    STEP(3, cD, TT - 1, "0",  0);
#undef STEP
#undef GISSUE
}

// ---------------------------------------------------------------------------
// Kernel 4 v23: standalone f16 readout. Thread-per-token; w1h/w2h/biases in
// LDS (72.6KB -> 2 blocks/CU = 8 waves/CU, r11-proven occupancy); fdot2
// everywhere; w1-row reads are wave-uniform LDS broadcasts; packed latent
// (128B/token). ~2x less work + traffic than r11's f32 form.
// ---------------------------------------------------------------------------
__global__ void __launch_bounds__(256) k_final(
    const unsigned* __restrict__ lath, const int* __restrict__ qseq,
    const unsigned* __restrict__ w1h, const float* __restrict__ la_b1,
    const unsigned* __restrict__ w2h, const float* __restrict__ la_b2,
    const int* __restrict__ q2c,
    const float* __restrict__ disc, const float* __restrict__ qds,
    const float* __restrict__ wdk, float* __restrict__ out)
{
    __shared__ unsigned s_w1[132 * 32];   // 16.9KB
    __shared__ unsigned s_w2[200 * 68];   // 54.4KB
    __shared__ float s_b1[132], s_b2[200];

    const int tid = threadIdx.x;
    for (int i = tid; i < 132 * 32; i += 256) s_w1[i] = w1h[i];
    for (int i = tid; i < 200 * 68; i += 256) s_w2[i] = w2h[i];
    if (tid < 132) s_b1[tid] = la_b1[tid];
    if (tid < 200) s_b2[tid] = la_b2[tid];
    __syncthreads();

    int o = blockIdx.x * 256 + tid;
    if (o >= BB * (TT - 1)) return;
    int b = o / (TT - 1), t = o - b * (TT - 1);

    unsigned L[32];
    {
        const uint4* lp = (const uint4*)(lath + ((size_t)(b * TT + t)) * 32);
        #pragma unroll
        for (int k4 = 0; k4 < 8; k4++) {
            uint4 v = lp[k4];
            L[4 * k4] = v.x; L[4 * k4 + 1] = v.y; L[4 * k4 + 2] = v.z; L[4 * k4 + 3] = v.w;
        }
    }

    unsigned hidpk[66];
    float hprev = 0.f;
    #pragma unroll
    for (int m = 0; m < 132; m++) {
        const unsigned* w1r = s_w1 + m * 32;
        float a0 = 0.f, a1 = 0.f, a2 = 0.f, a3 = 0.f;
        #pragma unroll
        for (int k = 0; k < 32; k += 4) {
            a0 = fdot2u(w1r[k],     L[k],     a0);
            a1 = fdot2u(w1r[k + 1], L[k + 1], a1);
            a2 = fdot2u(w1r[k + 2], L[k + 2], a2);
            a3 = fdot2u(w1r[k + 3], L[k + 3], a3);
        }
        float hm = fmaxf(((a0 + a1) + (a2 + a3)) + s_b1[m], 0.f);
        if (m & 1) hidpk[m >> 1] = packh_rtne(hprev, hm);
        else hprev = hm;
    }

    int q = qseq[b * TT + t + 1];
    float u[4];
    #pragma unroll
    for (int kc = 0; kc < 4; kc++) {
        int c = q2c[q * 4 + kc];
        const unsigned* w2r = s_w2 + c * 68;
        float u0 = 0.f, u1 = 0.f;
        #pragma unroll
        for (int k = 0; k < 66; k += 2) {
            u0 = fdot2u(w2r[k],     hidpk[k],     u0);
            u1 = fdot2u(w2r[k + 1], hidpk[k + 1], u1);
        }
        u[kc] = u0 + u1 + s_b2[c];
    }

    float us = 0.f;
    #pragma unroll
    for (int kc = 0; kc < 4; kc++) us += wdk[q * 4 + kc] * sigm(u[kc]);
    float qs = qds[q];
    float y = disc[q] * (us - qs) / (qs + 1e-6f);
    out[o] = sigm(y);
}

// ---------------------------------------------------------------------------
extern "C" void kernel_launch(void* const* d_in, const int* in_sizes, int n_in,
                              void* d_out, int out_size, void* d_ws, size_t ws_size,
                              hipStream_t stream)
{
    const float* E_q    = (const float*)d_in[0];
    const float* E_c    = (const float*)d_in[1];
    const float* E_it   = (const float*)d_in[2];
    const float* E_ut   = (const float*)d_in[3];
    const float* E_nh   = (const float*)d_in[4];
    const float* W_fuse = (const float*)d_in[5];
    const float* b_fuse = (const float*)d_in[6];
    const float* W_ih   = (const float*)d_in[7];
    const float* b_ih   = (const float*)d_in[8];
    const float* W_hh   = (const float*)d_in[9];
    const float* b_hh   = (const float*)d_in[10];
    const float* qd_W1  = (const float*)d_in[11];
    const float* qd_b1  = (const float*)d_in[12];
    const float* qd_W2  = (const float*)d_in[13];
    const float* qd_b2  = (const float*)d_in[14];
    const float* la_W1  = (const float*)d_in[15];
    const float* la_b1  = (const float*)d_in[16];
    const float* la_W2  = (const float*)d_in[17];
    const float* la_b2  = (const float*)d_in[18];
    const float* dc_W1  = (const float*)d_in[19];
    const float* dc_b1  = (const float*)d_in[20];
    const float* dc_W2  = (const float*)d_in[21];
    const float* dc_b2  = (const float*)d_in[22];

    int off = (in_sizes[23] == QN * 200) ? 1 : 0;
    const int* qseq  = (const int*)d_in[23 + off];
    const int* cseq  = (const int*)d_in[24 + off];
    const int* itseq = (const int*)d_in[25 + off];
    const int* utseq = (const int*)d_in[26 + off];
    const int* nhseq = (const int*)d_in[27 + off];
    const int* naseq = (const int*)d_in[28 + off];
    const int* q2c   = (const int*)d_in[29 + off];
    const int* q2cm  = (const int*)d_in[30 + off];

    float* ws = (float*)d_ws;
    size_t o = 0;
    float* T_c  = ws + o; o += (size_t)201 * 192;
    float* Tit  = ws + o; o += (size_t)101 * 256;
    float* Tut  = ws + o; o += (size_t)101 * 256;
    float* Tnh  = ws + o; o += (size_t)101 * 256;
    float* Tna  = ws + o; o += (size_t)101 * 256;
    float* b0   = ws + o; o += 192;
    float* vc   = ws + o; o += 192;
    float* Xq   = ws + o; o += (size_t)QN * 256;
    float* disc = ws + o; o += QN;
    float* qds  = ws + o; o += QN;
    float* wdk  = ws + o; o += (size_t)QN * 4;
    unsigned* w1h = (unsigned*)(ws + o); o += (size_t)132 * 32;
    unsigned* w2h = (unsigned*)(ws + o); o += (size_t)200 * 68;
    unsigned* lath = (unsigned*)(ws + o); o += (size_t)BB * TT * 32;

    float* outp = (float*)d_out;

    k_tables<<<699, 192, 0, stream>>>(E_c, E_it, E_ut, E_nh, W_fuse, b_fuse, W_ih, b_ih,
                                      la_W1, la_W2,
                                      T_c, Tit, Tut, Tnh, Tna, b0, vc, w1h, w2h);
    k_perq<<<(QN + QPB - 1) / QPB, 192, 0, stream>>>(E_q, W_ih, qd_W1, qd_b1, qd_W2, qd_b2,
                                                     dc_W1, dc_b1, dc_W2, dc_b2, q2c, q2cm, T_c,
                                                     Xq, disc, qds, wdk);
    k_gru<<<BB, 64, 0, stream>>>(W_hh, b_hh, Xq, Tit, Tut, Tnh, Tna, b0, vc,
                                 qseq, cseq, itseq, utseq, nhseq, naseq, lath);
    k_final<<<(BB * (TT - 1) + 255) / 256, 256, 0, stream>>>(lath, qseq, w1h, la_b1,
                                                             w2h, la_b2, q2c, disc, qds, wdk, outp);
}